// Round 1
// baseline (17206.552 us; speedup 1.0000x reference)
//
#include <hip/hip_runtime.h>
#include <hip/hip_bf16.h>

#define FEATURES 128
#define NEURONS  512
#define THETA    256
#define KCAT     896   // 512 (x) + 256 (s) + 128 (I)
#define TT       2048
#define BB       64

typedef unsigned int uint32;
using bf16 = __hip_bfloat16;

// Weight prep: convert to bf16 in transposed, k-paired layouts.
// Wcat2: [448][256][2] bf16  -> element (k2, j, kk) = W_cat[k=2*k2+kk][j]
//        where cat-k order: [0,512)=x part of W_ih, [512,768)=W_hh, [768,896)=I part of W_ih
// Wout2: [128][512][2] bf16  -> element (k2, n, kk) = W_out[n][2*k2+kk]
__global__ void prep_kernel(const float* __restrict__ W_ih,
                            const float* __restrict__ W_hh,
                            const float* __restrict__ W_out,
                            bf16* __restrict__ Wcat2,
                            bf16* __restrict__ Wout2)
{
    int e = blockIdx.x * blockDim.x + threadIdx.x;
    const int NCAT = 448 * 256 * 2;   // 229376
    const int NOUT = 128 * 512 * 2;   // 131072
    if (e < NCAT) {
        int k2 = e >> 9; int rem = e & 511; int j = rem >> 1; int kk = rem & 1;
        int k = 2 * k2 + kk;
        float v;
        if (k < 512)      v = W_ih[j * 640 + k];              // x part
        else if (k < 768) v = W_hh[j * 256 + (k - 512)];      // s part
        else              v = W_ih[j * 640 + 512 + (k - 768)];// I part
        Wcat2[e] = __float2bfloat16(v);
    } else if (e < NCAT + NOUT) {
        int e2 = e - NCAT;
        int k2 = e2 >> 10; int rem = e2 & 1023; int n = rem >> 1; int kk = rem & 1;
        Wout2[e2] = __float2bfloat16(W_out[n * 256 + 2 * k2 + kk]);
    }
}

// One workgroup per batch element; whole time loop in-kernel; weights streamed
// from L2 each step; activations/state fp32 in LDS.
__global__ __launch_bounds__(1024)
void scan_kernel(const float* __restrict__ I,
                 const float* __restrict__ b_ih, const float* __restrict__ b_hh,
                 const float* __restrict__ b_out, const float* __restrict__ A,
                 const uint32* __restrict__ Wcat2, const uint32* __restrict__ Wout2,
                 float* __restrict__ out)
{
    __shared__ float act[KCAT];      // [x 0:512 | s 512:768 | I 768:896]
    __shared__ float part[1024];
    __shared__ float sbuf[THETA];
    __shared__ float pb[1024];
    __shared__ float bsum[THETA];
    __shared__ float bo[NEURONS];
    __shared__ float Av[NEURONS];

    const int tid = threadIdx.x;
    const int b   = blockIdx.x;

    if (tid < THETA)   bsum[tid] = b_ih[tid] + b_hh[tid];
    if (tid < NEURONS) { bo[tid] = b_out[tid]; Av[tid] = A[tid]; }
    if (tid < NEURONS + THETA) act[tid] = 0.0f;   // x=0, s=0
    __syncthreads();

    const int kq = tid >> 8;   // 0..3  (phase A k-quarter)
    const int j  = tid & 255;  //       (phase A output row)
    const int kh = tid >> 9;   // 0..1  (phase B k-half)
    const int n  = tid & 511;  //       (phase B output row)

    const float2* act2  = (const float2*)act;
    const float2* sbuf2 = (const float2*)sbuf;

    for (int t = 0; t < TT; ++t) {
        // stage I_t
        if (tid < FEATURES)
            act[NEURONS + THETA + tid] = I[((size_t)b * TT + t) * FEATURES + tid];
        __syncthreads();

        // ---- phase A: pre[j] partial over k-quarter ----
        {
            float acc = 0.f;
            const int k2b = kq * 112;
            #pragma unroll 8
            for (int k2 = k2b; k2 < k2b + 112; ++k2) {
                uint32 wv = Wcat2[(size_t)k2 * 256 + j];   // 2 bf16 weights (k even/odd)
                float2 a  = act2[k2];                      // broadcast LDS read
                acc = fmaf(a.x, __uint_as_float(wv << 16), acc);
                acc = fmaf(a.y, __uint_as_float(wv & 0xffff0000u), acc);
            }
            part[tid] = acc;   // tid == kq*256 + j
        }
        __syncthreads();
        if (tid < THETA) {
            float pre = part[tid] + part[tid + 256] + part[tid + 512] + part[tid + 768]
                      + bsum[tid];
            float s = tanhf(pre);
            sbuf[tid] = s;
            act[NEURONS + tid] = s;   // s state for step t+1 (old s already consumed)
        }
        __syncthreads();

        // ---- phase B: f[n] partial over k-half ----
        {
            float acc = 0.f;
            const int k2b = kh * 64;
            #pragma unroll 8
            for (int k2 = k2b; k2 < k2b + 64; ++k2) {
                uint32 wv = Wout2[(size_t)k2 * 512 + n];
                float2 sv = sbuf2[k2];
                acc = fmaf(sv.x, __uint_as_float(wv << 16), acc);
                acc = fmaf(sv.y, __uint_as_float(wv & 0xffff0000u), acc);
            }
            pb[tid] = acc;   // tid == kh*512 + n
        }
        __syncthreads();
        if (tid < NEURONS) {
            float f = pb[tid] + pb[tid + 512] + bo[tid];
            f = fmaxf(f, 0.f);
            float xo = act[tid];
            float xn = (xo + 0.1f * f * Av[tid]) / (1.1f + 0.1f * f);
            act[tid] = xn;            // x state for step t+1
            out[((size_t)b * TT + t) * NEURONS + tid] = xn;
        }
        // no trailing sync needed: next-iter I_t write is disjoint; the
        // post-I_t __syncthreads orders act[] x-writes vs phase-A reads.
    }
}

extern "C" void kernel_launch(void* const* d_in, const int* in_sizes, int n_in,
                              void* d_out, int out_size, void* d_ws, size_t ws_size,
                              hipStream_t stream)
{
    const float* I     = (const float*)d_in[0];
    const float* W_ih  = (const float*)d_in[1];
    const float* W_hh  = (const float*)d_in[2];
    const float* b_ih  = (const float*)d_in[3];
    const float* b_hh  = (const float*)d_in[4];
    const float* W_out = (const float*)d_in[5];
    const float* b_out = (const float*)d_in[6];
    const float* A     = (const float*)d_in[7];

    bf16* Wcat2 = (bf16*)d_ws;                                   // 229376 bf16
    bf16* Wout2 = (bf16*)((char*)d_ws + 229376 * sizeof(bf16));  // 131072 bf16

    const int total = 229376 + 131072;
    prep_kernel<<<(total + 1023) / 1024, 1024, 0, stream>>>(W_ih, W_hh, W_out, Wcat2, Wout2);
    scan_kernel<<<BB, 1024, 0, stream>>>(I, b_ih, b_hh, b_out, A,
                                         (const uint32*)Wcat2, (const uint32*)Wout2,
                                         (float*)d_out);
}